// Round 2
// baseline (19169.257 us; speedup 1.0000x reference)
//
#include <hip/hip_runtime.h>
#include <cstdint>
#include <cstddef>

// ============================================================================
// Attention seq2seq: B=64 S=256 T=128(dec 127) E=256 H=512 Vtgt=16000
// Round 2: hi/lo split-bf16 (~fp32) on every recurrent / recurrence-feeding
// path to kill bf16 drift (round 1: absmax 0.117 vs 0.109 threshold).
// ============================================================================

typedef __attribute__((ext_vector_type(4))) float f32x4;
typedef __attribute__((ext_vector_type(8))) short s16x8;
typedef __attribute__((ext_vector_type(4))) unsigned int u32x4;

#define DEV __device__ __forceinline__

// ---------------- d_out scratch arena (bytes). out = 130,048,000 f32 = 520,192,000 B
#define OFF_PREF   0ull
#define OFF_PREB   (OFF_PREF + 16384ull*2048*4)
#define OFF_PRED   (OFF_PREB + 16384ull*2048*4)
#define OFF_ASRC   (OFF_PRED + 8192ull*2048*4)
#define OFF_ATGT   (OFF_ASRC + 16384ull*256*2)
#define OFF_ECH    (OFF_ATGT + 8192ull*256*2)    // enc_cat hi [16384][1024] bf16
#define OFF_ECL    (OFF_ECH + 16384ull*1024*2)   // enc_cat lo
#define OFF_EP     (OFF_ECL + 16384ull*1024*2)
#define OFF_EHP    (OFF_EP + 16384ull*512*4)
#define OFF_WIHF   (OFF_EHP + 16384ull*512*4)
#define OFF_WIHB   (OFF_WIHF + 2048ull*256*2)
#define OFF_WX     (OFF_WIHB + 2048ull*256*2)
#define OFF_WHHFH  (OFF_WX + 2048ull*256*2)
#define OFF_WHHFL  (OFF_WHHFH + 2048ull*512*2)
#define OFF_WHHBH  (OFF_WHHFL + 2048ull*512*2)
#define OFF_WHHBL  (OFF_WHHBH + 2048ull*512*2)
#define OFF_WATTH  (OFF_WHHBL + 2048ull*512*2)
#define OFF_WATTL  (OFF_WATTH + 512ull*1024*2)
#define OFF_WC1H   (OFF_WATTL + 512ull*1024*2)
#define OFF_WC1L   (OFF_WC1H + 512ull*1024*2)
#define OFF_WC2TF  (OFF_WC1L + 512ull*1024*2)    // fp32 [512 k][512 j]
#define OFF_WOH    (OFF_WC2TF + 512ull*512*4)
#define OFF_WOL    (OFF_WOH + 2048ull*512*2)
#define OFF_DWHHH  (OFF_WOL + 2048ull*512*2)
#define OFF_DWHHL  (OFF_DWHHH + 2048ull*512*2)
#define OFF_WHIH   (OFF_DWHHL + 2048ull*512*2)
#define OFF_WHIL   (OFF_WHIH + 512ull*1024*2)
#define OFF_WCIH   (OFF_WHIL + 512ull*1024*2)
#define OFF_WCIL   (OFF_WCIH + 512ull*1024*2)
#define OFF_HENCH  (OFF_WCIL + 512ull*1024*2)    // [2 ping][2 dir][64][512] bf16
#define OFF_HENCL  (OFF_HENCH + 2ull*2*64*512*2)
#define OFF_HCATH  (OFF_HENCL + 2ull*2*64*512*2) // [128 pad][1024] bf16
#define OFF_HCATL  (OFF_HCATH + 128ull*1024*2)
#define OFF_CCATH  (OFF_HCATL + 128ull*1024*2)
#define OFF_CCATL  (OFF_CCATH + 128ull*1024*2)
#define OFF_DH0    (OFF_CCATL + 128ull*1024*2)   // [128 pad][512] f32
#define OFF_DC0    (OFF_DH0 + 128ull*512*4)
#define OFF_HDBH   (OFF_DC0 + 128ull*512*4)      // [2 ping][64][512] bf16
#define OFF_HDBL   (OFF_HDBH + 2ull*64*512*2)
#define OFF_HDF    (OFF_HDBL + 2ull*64*512*2)    // [2 ping][64][512] f32
#define OFF_CBCH   (OFF_HDF + 2ull*64*512*4)     // [64][512] bf16 comb broadcast
#define OFF_CBCL   (OFF_CBCH + 64ull*512*2)
#define OFF_CTRL   (OFF_CBCL + 64ull*512*2)
#define OFF_END    (OFF_CTRL + 4096ull)
static_assert(OFF_END <= 520192000ull, "arena overflow");

// ---------------- ws layout: only what the FINAL gemm needs
#define WOFF_COMB  0ull                           // [8192 pad][512] bf16
#define WOFF_WVOC  (WOFF_COMB + 8192ull*512*2)    // [16000][512] bf16

// ---------------- helpers
DEV float bf2f(unsigned short u) { return __uint_as_float(((unsigned)u) << 16); }
DEV unsigned short f2bf(float f) {
  unsigned u = __float_as_uint(f);
  u += 0x7fffu + ((u >> 16) & 1u);
  return (unsigned short)(u >> 16);
}
DEV float sigm(float x)   { return __builtin_amdgcn_rcpf(1.f + __expf(-x)); }
DEV float tanh_f(float x) { return 1.f - 2.f * __builtin_amdgcn_rcpf(1.f + __expf(2.f * x)); }

// device-scope barrier among co-resident blocks (cooperative launch).
DEV void gbar(unsigned int* cnt, unsigned int target) {
  __syncthreads();
  if (threadIdx.x == 0) {
    __hip_atomic_fetch_add(cnt, 1u, __ATOMIC_RELEASE, __HIP_MEMORY_SCOPE_AGENT);
    while (__hip_atomic_load(cnt, __ATOMIC_ACQUIRE, __HIP_MEMORY_SCOPE_AGENT) < target)
      __builtin_amdgcn_s_sleep(1);
  }
  __syncthreads();
}

// ---------------- small utility kernels
__global__ void k_cast_slice(const float* __restrict__ src, unsigned short* __restrict__ dst,
                             int rows, int cols, int pitch, int off) {
  int id = blockIdx.x * 256 + threadIdx.x;
  if (id < rows * cols) {
    int r = id / cols, c = id - r * cols;
    dst[id] = f2bf(src[(size_t)r * pitch + off + c]);
  }
}

__global__ void k_cast_split(const float* __restrict__ src, unsigned short* __restrict__ hi,
                             unsigned short* __restrict__ lo, int rows, int cols, int pitch, int off) {
  int id = blockIdx.x * 256 + threadIdx.x;
  if (id < rows * cols) {
    int r = id / cols, c = id - r * cols;
    float v = src[(size_t)r * pitch + off + c];
    unsigned short h = f2bf(v);
    hi[id] = h;
    lo[id] = f2bf(v - bf2f(h));
  }
}

// wc2tf[k][j] = W_comb[j][1024+k]  (fp32, transposed for coalesced per-j reads)
__global__ void k_wc2tf(const float* __restrict__ wcomb, float* __restrict__ out) {
  int id = blockIdx.x * 256 + threadIdx.x;   // 262144
  int j = id & 511, k = id >> 9;
  out[(size_t)k * 512 + j] = wcomb[(size_t)j * 1536 + 1024 + k];
}

// A[r][e] = bf16(emb[sents[b][t]][e]),  r = t*64+b
__global__ void k_embed(const int* __restrict__ sents, const float* __restrict__ emb,
                        unsigned short* __restrict__ A, int sent_stride) {
  int r = blockIdx.x;
  int b = r & 63, t = r >> 6;
  int tok = sents[b * sent_stride + t];
  A[(size_t)r * 256 + threadIdx.x] = f2bf(emb[(size_t)tok * 256 + threadIdx.x]);
}

// ---------------- generic bf16 MFMA GEMM: C(M,N) (+)= A(M,K)bf16 @ W(N,K)bf16^T
__global__ __launch_bounds__(256) void k_gemm(const unsigned short* __restrict__ A,
                                              const unsigned short* __restrict__ W,
                                              float* __restrict__ C, int M, int N, int K,
                                              int accum) {
  __shared__ unsigned short As[128][72];
  __shared__ unsigned short Bs[128][72];
  const int m0 = blockIdx.y * 128, n0 = blockIdx.x * 128;
  const int tid = threadIdx.x;
  const int wave = tid >> 6, lane = tid & 63, quad = lane >> 4, l15 = lane & 15;
  const int wm = (wave >> 1) * 64, wn = (wave & 1) * 64;
  const int srow = tid >> 1, sseg = (tid & 1) * 32;
  f32x4 acc[4][4] = {};
  for (int k0 = 0; k0 < K; k0 += 64) {
    const unsigned short* ap = A + (size_t)(m0 + srow) * K + k0 + sseg;
    const unsigned short* wp = W + (size_t)(n0 + srow) * K + k0 + sseg;
    u32x4 a0 = *(const u32x4*)(ap);      u32x4 a1 = *(const u32x4*)(ap + 8);
    u32x4 a2 = *(const u32x4*)(ap + 16); u32x4 a3 = *(const u32x4*)(ap + 24);
    u32x4 b0 = *(const u32x4*)(wp);      u32x4 b1 = *(const u32x4*)(wp + 8);
    u32x4 b2 = *(const u32x4*)(wp + 16); u32x4 b3 = *(const u32x4*)(wp + 24);
    __syncthreads();
    *(u32x4*)&As[srow][sseg]      = a0; *(u32x4*)&As[srow][sseg + 8]  = a1;
    *(u32x4*)&As[srow][sseg + 16] = a2; *(u32x4*)&As[srow][sseg + 24] = a3;
    *(u32x4*)&Bs[srow][sseg]      = b0; *(u32x4*)&Bs[srow][sseg + 8]  = b1;
    *(u32x4*)&Bs[srow][sseg + 16] = b2; *(u32x4*)&Bs[srow][sseg + 24] = b3;
    __syncthreads();
#pragma unroll
    for (int kk = 0; kk < 64; kk += 32) {
      s16x8 af[4], bf[4];
#pragma unroll
      for (int i = 0; i < 4; ++i) af[i] = *(const s16x8*)&As[wm + i * 16 + l15][kk + quad * 8];
#pragma unroll
      for (int i = 0; i < 4; ++i) bf[i] = *(const s16x8*)&Bs[wn + i * 16 + l15][kk + quad * 8];
#pragma unroll
      for (int mi = 0; mi < 4; ++mi)
#pragma unroll
        for (int ni = 0; ni < 4; ++ni)
          acc[mi][ni] = __builtin_amdgcn_mfma_f32_16x16x32_bf16(af[mi], bf[ni], acc[mi][ni], 0, 0, 0);
    }
  }
#pragma unroll
  for (int mi = 0; mi < 4; ++mi)
#pragma unroll
    for (int ni = 0; ni < 4; ++ni)
#pragma unroll
      for (int r = 0; r < 4; ++r) {
        int row = m0 + wm + mi * 16 + quad * 4 + r;
        int col = n0 + wn + ni * 16 + l15;
        if (row < M) {
          size_t idx = (size_t)row * N + col;
          C[idx] = (accum ? C[idx] : 0.f) + acc[mi][ni][r];
        }
      }
}

// ---------------- persistent encoder: 64 blocks (32/dir), 256 thr, 1 barrier/step
// 3-term split-bf16 recurrent GEMM: h and Whh both hi/lo.
__global__ __launch_bounds__(256, 1) void k_encoder(
    const float* __restrict__ preF, const float* __restrict__ preB,
    const unsigned short* __restrict__ WhhFh, const unsigned short* __restrict__ WhhFl,
    const unsigned short* __restrict__ WhhBh, const unsigned short* __restrict__ WhhBl,
    const float* __restrict__ bihF, const float* __restrict__ bhhF,
    const float* __restrict__ bihB, const float* __restrict__ bhhB,
    unsigned short* __restrict__ hpingH, unsigned short* __restrict__ hpingL,
    unsigned short* __restrict__ encH, unsigned short* __restrict__ encL,
    unsigned short* __restrict__ hcatH, unsigned short* __restrict__ hcatL,
    unsigned short* __restrict__ ccatH, unsigned short* __restrict__ ccatL,
    unsigned int* cnt) {
  const int blk = blockIdx.x, dir = blk >> 5, j0 = (blk & 31) << 4;
  const int tid = threadIdx.x, wave = tid >> 6, lane = tid & 63, quad = lane >> 4, l15 = lane & 15;
  const float* pre = dir ? preB : preF;
  const unsigned short* Wh = dir ? WhhBh : WhhFh;
  const unsigned short* Wl = dir ? WhhBl : WhhFl;
  const float* bihp = dir ? bihB : bihF;
  const float* bhhp = dir ? bhhB : bhhF;
  const int j = j0 + l15;
  const int bb = wave * 16 + quad * 4;
  float bias[4];
#pragma unroll
  for (int g = 0; g < 4; ++g) bias[g] = bihp[g * 512 + j] + bhhp[g * 512 + j];
  for (int idx = blk * 256 + tid; idx < 2 * 64 * 512; idx += 64 * 256) {
    hpingH[idx] = 0; hpingL[idx] = 0;   // h_{-1}=0 (ping 0, both dirs)
  }
  float c_reg[4] = {0.f, 0.f, 0.f, 0.f};
  unsigned ep_n = 0;
  gbar(cnt, 64u * (++ep_n));
  for (int i = 0; i < 256; ++i) {
    const int t = dir ? (255 - i) : i;
    const size_t rdo = (size_t)((i & 1) * 2 + dir) * (64 * 512);
    const size_t wro = (size_t)(((i + 1) & 1) * 2 + dir) * (64 * 512);
    float pv[4][4];
#pragma unroll
    for (int g = 0; g < 4; ++g)
#pragma unroll
      for (int r = 0; r < 4; ++r)
        pv[g][r] = pre[(size_t)(t * 64 + bb + r) * 2048 + g * 512 + j];
    f32x4 acc[4] = {};
    const unsigned short* arowH = hpingH + rdo + (wave * 16 + l15) * 512 + quad * 8;
    const unsigned short* arowL = hpingL + rdo + (wave * 16 + l15) * 512 + quad * 8;
    const unsigned short* wrowH = Wh + (size_t)(j0 + l15) * 512 + quad * 8;
    const unsigned short* wrowL = Wl + (size_t)(j0 + l15) * 512 + quad * 8;
#pragma unroll 4
    for (int kb = 0; kb < 16; ++kb) {
      s16x8 ah = *(const s16x8*)(arowH + kb * 32);
      s16x8 al = *(const s16x8*)(arowL + kb * 32);
#pragma unroll
      for (int g = 0; g < 4; ++g) {
        s16x8 bh = *(const s16x8*)(wrowH + (size_t)g * 512 * 512 + kb * 32);
        s16x8 bl = *(const s16x8*)(wrowL + (size_t)g * 512 * 512 + kb * 32);
        acc[g] = __builtin_amdgcn_mfma_f32_16x16x32_bf16(ah, bh, acc[g], 0, 0, 0);
        acc[g] = __builtin_amdgcn_mfma_f32_16x16x32_bf16(al, bh, acc[g], 0, 0, 0);
        acc[g] = __builtin_amdgcn_mfma_f32_16x16x32_bf16(ah, bl, acc[g], 0, 0, 0);
      }
    }
#pragma unroll
    for (int r = 0; r < 4; ++r) {
      int b = bb + r;
      float gi = acc[0][r] + pv[0][r] + bias[0];
      float gf = acc[1][r] + pv[1][r] + bias[1];
      float gg = acc[2][r] + pv[2][r] + bias[2];
      float go = acc[3][r] + pv[3][r] + bias[3];
      float c2 = sigm(gf) * c_reg[r] + sigm(gi) * tanh_f(gg);
      float h2 = sigm(go) * tanh_f(c2);
      c_reg[r] = c2;
      unsigned short hh = f2bf(h2);
      unsigned short hl = f2bf(h2 - bf2f(hh));
      hpingH[wro + b * 512 + j] = hh;
      hpingL[wro + b * 512 + j] = hl;
      size_t ei = ((size_t)b * 256 + t) * 1024 + dir * 512 + j;
      encH[ei] = hh; encL[ei] = hl;
      if (i == 255) {
        unsigned short ch = f2bf(c2);
        hcatH[b * 1024 + dir * 512 + j] = hh;
        hcatL[b * 1024 + dir * 512 + j] = hl;
        ccatH[b * 1024 + dir * 512 + j] = ch;
        ccatL[b * 1024 + dir * 512 + j] = f2bf(c2 - bf2f(ch));
      }
    }
    gbar(cnt, 64u * (++ep_n));
  }
}

// ---------------- persistent decoder: 96 blocks x 512 thr.
// blocks 0..31: gate blocks (waves 0-3 active, 16 j each, 3-term MFMA x2 GEMMs)
// blocks 32..95: attention blocks (one per batch), fp32 VALU. 2 barriers/step.
__global__ __launch_bounds__(512, 1) void k_decoder(
    const float* __restrict__ preD,
    const unsigned short* __restrict__ WoH, const unsigned short* __restrict__ WoL,
    const unsigned short* __restrict__ dWhhH, const unsigned short* __restrict__ dWhhL,
    const float* __restrict__ dbih, const float* __restrict__ dbhh,
    const float* __restrict__ dh0, const float* __restrict__ dc0,
    const float* __restrict__ ep, const float* __restrict__ ehp,
    const float* __restrict__ wc2tf,
    unsigned short* __restrict__ hbH, unsigned short* __restrict__ hbL,
    float* __restrict__ hf32,
    unsigned short* __restrict__ cbH, unsigned short* __restrict__ cbL,
    unsigned short* __restrict__ comb_all,
    unsigned int* cnt) {
  __shared__ float hL[512];
  __shared__ float attL[256];
  __shared__ float red[16];
  const int blk = blockIdx.x, tid = threadIdx.x;
  unsigned ep_n = 0;
  if (blk >= 32) {
    const int b = blk - 32;
    {  // publish h_{-1} = dec_h0 (ping 0) as hi/lo + fp32
      float v = dh0[b * 512 + tid];
      unsigned short h = f2bf(v);
      hbH[(size_t)b * 512 + tid] = h;
      hbL[(size_t)b * 512 + tid] = f2bf(v - bf2f(h));
      hf32[(size_t)b * 512 + tid] = v;
    }
    gbar(cnt, 96u * (++ep_n));  // BAR0: h_{-1} visible
    gbar(cnt, 96u * (++ep_n));  // BAR1: h_0 visible (gate prologue)
    for (int t = 0; t < 127; ++t) {
      const int rd = (t & 1) ^ 1;
      hL[tid] = hf32[((size_t)rd * 64 + b) * 512 + tid];
      __syncthreads();
      {  // scores[s] = ep[b][s][:] . h   (2 threads per s)
        const int s = tid >> 1, half = tid & 1;
        const float* eprow = ep + ((size_t)b * 256 + s) * 512 + half * 256;
        const float* hh = hL + half * 256;
        float p = 0.f;
#pragma unroll 8
        for (int k = 0; k < 256; k += 4) {
          f32x4 e = *(const f32x4*)(eprow + k);
          f32x4 hv = *(const f32x4*)(hh + k);
          p = fmaf(e[0], hv[0], fmaf(e[1], hv[1], fmaf(e[2], hv[2], fmaf(e[3], hv[3], p))));
        }
        p += __shfl_xor(p, 1);
        if (half == 0) attL[s] = p;
      }
      __syncthreads();
      float m_;
      {
        float v = (tid < 256) ? attL[tid] : -3.4e38f;
#pragma unroll
        for (int o = 32; o; o >>= 1) v = fmaxf(v, __shfl_xor(v, o));
        if ((tid & 63) == 0) red[tid >> 6] = v;
        __syncthreads();
        m_ = red[0];
#pragma unroll
        for (int w = 1; w < 8; ++w) m_ = fmaxf(m_, red[w]);
      }
      float lse;
      {
        float v = (tid < 256) ? __expf(attL[tid] - m_) : 0.f;
#pragma unroll
        for (int o = 32; o; o >>= 1) v += __shfl_xor(v, o);
        if ((tid & 63) == 0) red[8 + (tid >> 6)] = v;
        __syncthreads();
        float sum = 0.f;
#pragma unroll
        for (int w = 0; w < 8; ++w) sum += red[8 + w];
        lse = m_ + __logf(sum);
      }
      if (tid < 256) attL[tid] -= lse;   // log-softmax (ref uses LOG probs)
      __syncthreads();
      float a_ = 0.f;  // ctx_proj[j=tid] = sum_s att[s]*ehp[b][s][j]
      {
        const float* eb = ehp + ((size_t)b * 256) * 512 + tid;
#pragma unroll 4
        for (int s = 0; s < 256; ++s) a_ = fmaf(attL[s], eb[(size_t)s * 512], a_);
      }
      // (Wc2 @ h)[j=tid] in fp32 (weight exact)
      float w0 = 0.f, w1 = 0.f, w2 = 0.f, w3 = 0.f;
      {
        const float* wc = wc2tf + tid;
#pragma unroll 4
        for (int k = 0; k < 512; k += 4) {
          w0 = fmaf(hL[k],     wc[(size_t)(k)     * 512], w0);
          w1 = fmaf(hL[k + 1], wc[(size_t)(k + 1) * 512], w1);
          w2 = fmaf(hL[k + 2], wc[(size_t)(k + 2) * 512], w2);
          w3 = fmaf(hL[k + 3], wc[(size_t)(k + 3) * 512], w3);
        }
      }
      float comb = tanh_f(a_ + (w0 + w1) + (w2 + w3));
      unsigned short ch = f2bf(comb);
      cbH[b * 512 + tid] = ch;
      cbL[b * 512 + tid] = f2bf(comb - bf2f(ch));
      comb_all[((size_t)b * 127 + t) * 512 + tid] = ch;
      gbar(cnt, 96u * (++ep_n));  // BAR alpha: comb_t visible
      gbar(cnt, 96u * (++ep_n));  // BAR beta: h_{t+1} visible
    }
  } else {
    const int j0 = blk << 4;
    const int wave = tid >> 6, lane = tid & 63, quad = lane >> 4, l15 = lane & 15;
    const int j = j0 + l15;
    const int bb = (wave & 3) * 16 + quad * 4;
    const bool act = wave < 4;
    float bias[4] = {}, c_reg[4] = {};
    if (act) {
#pragma unroll
      for (int g = 0; g < 4; ++g) bias[g] = dbih[g * 512 + j] + dbhh[g * 512 + j];
#pragma unroll
      for (int r = 0; r < 4; ++r) c_reg[r] = dc0[(bb + r) * 512 + j];
    }
    gbar(cnt, 96u * (++ep_n));  // BAR0
    if (act) {  // prologue: gates_0 = dWhh@dec_h0 + pre_0 + bias  (o_prev = 0)
      f32x4 acc[4] = {};
      const unsigned short* aH = hbH + ((wave & 3) * 16 + l15) * 512 + quad * 8;
      const unsigned short* aL = hbL + ((wave & 3) * 16 + l15) * 512 + quad * 8;
      const unsigned short* wH = dWhhH + (size_t)(j0 + l15) * 512 + quad * 8;
      const unsigned short* wL = dWhhL + (size_t)(j0 + l15) * 512 + quad * 8;
#pragma unroll 4
      for (int kb = 0; kb < 16; ++kb) {
        s16x8 ah = *(const s16x8*)(aH + kb * 32);
        s16x8 al = *(const s16x8*)(aL + kb * 32);
#pragma unroll
        for (int g = 0; g < 4; ++g) {
          s16x8 bh = *(const s16x8*)(wH + (size_t)g * 512 * 512 + kb * 32);
          s16x8 bl = *(const s16x8*)(wL + (size_t)g * 512 * 512 + kb * 32);
          acc[g] = __builtin_amdgcn_mfma_f32_16x16x32_bf16(ah, bh, acc[g], 0, 0, 0);
          acc[g] = __builtin_amdgcn_mfma_f32_16x16x32_bf16(al, bh, acc[g], 0, 0, 0);
          acc[g] = __builtin_amdgcn_mfma_f32_16x16x32_bf16(ah, bl, acc[g], 0, 0, 0);
        }
      }
#pragma unroll
      for (int r = 0; r < 4; ++r) {
        int b = bb + r;
        float gi = acc[0][r] + preD[(size_t)b * 2048 + 0 * 512 + j] + bias[0];
        float gf = acc[1][r] + preD[(size_t)b * 2048 + 1 * 512 + j] + bias[1];
        float gg = acc[2][r] + preD[(size_t)b * 2048 + 2 * 512 + j] + bias[2];
        float go = acc[3][r] + preD[(size_t)b * 2048 + 3 * 512 + j] + bias[3];
        float c2 = sigm(gf) * c_reg[r] + sigm(gi) * tanh_f(gg);
        float h2 = sigm(go) * tanh_f(c2);
        c_reg[r] = c2;
        unsigned short hh = f2bf(h2);
        hbH[((size_t)64 + b) * 512 + j] = hh;
        hbL[((size_t)64 + b) * 512 + j] = f2bf(h2 - bf2f(hh));
        hf32[((size_t)64 + b) * 512 + j] = h2;
      }
    }
    gbar(cnt, 96u * (++ep_n));  // BAR1
    for (int t = 0; t < 127; ++t) {
      const int rd = (t & 1) ^ 1, wr = t & 1;
      f32x4 acc[4] = {};
      if (act && t < 126) {  // G1 = dWhh @ h_t (held in regs across barrier)
        const unsigned short* aH = hbH + (size_t)rd * 64 * 512 + ((wave & 3) * 16 + l15) * 512 + quad * 8;
        const unsigned short* aL = hbL + (size_t)rd * 64 * 512 + ((wave & 3) * 16 + l15) * 512 + quad * 8;
        const unsigned short* wH = dWhhH + (size_t)(j0 + l15) * 512 + quad * 8;
        const unsigned short* wL = dWhhL + (size_t)(j0 + l15) * 512 + quad * 8;
#pragma unroll 4
        for (int kb = 0; kb < 16; ++kb) {
          s16x8 ah = *(const s16x8*)(aH + kb * 32);
          s16x8 al = *(const s16x8*)(aL + kb * 32);
#pragma unroll
          for (int g = 0; g < 4; ++g) {
            s16x8 bh = *(const s16x8*)(wH + (size_t)g * 512 * 512 + kb * 32);
            s16x8 bl = *(const s16x8*)(wL + (size_t)g * 512 * 512 + kb * 32);
            acc[g] = __builtin_amdgcn_mfma_f32_16x16x32_bf16(ah, bh, acc[g], 0, 0, 0);
            acc[g] = __builtin_amdgcn_mfma_f32_16x16x32_bf16(al, bh, acc[g], 0, 0, 0);
            acc[g] = __builtin_amdgcn_mfma_f32_16x16x32_bf16(ah, bl, acc[g], 0, 0, 0);
          }
        }
      }
      gbar(cnt, 96u * (++ep_n));  // BAR alpha
      if (act && t < 126) {  // G2 += Wo @ comb_t ; then elementwise -> h_{t+1}
        const unsigned short* aH = cbH + ((wave & 3) * 16 + l15) * 512 + quad * 8;
        const unsigned short* aL = cbL + ((wave & 3) * 16 + l15) * 512 + quad * 8;
        const unsigned short* wH = WoH + (size_t)(j0 + l15) * 512 + quad * 8;
        const unsigned short* wL = WoL + (size_t)(j0 + l15) * 512 + quad * 8;
#pragma unroll 4
        for (int kb = 0; kb < 16; ++kb) {
          s16x8 ah = *(const s16x8*)(aH + kb * 32);
          s16x8 al = *(const s16x8*)(aL + kb * 32);
#pragma unroll
          for (int g = 0; g < 4; ++g) {
            s16x8 bh = *(const s16x8*)(wH + (size_t)g * 512 * 512 + kb * 32);
            s16x8 bl = *(const s16x8*)(wL + (size_t)g * 512 * 512 + kb * 32);
            acc[g] = __builtin_amdgcn_mfma_f32_16x16x32_bf16(ah, bh, acc[g], 0, 0, 0);
            acc[g] = __builtin_amdgcn_mfma_f32_16x16x32_bf16(al, bh, acc[g], 0, 0, 0);
            acc[g] = __builtin_amdgcn_mfma_f32_16x16x32_bf16(ah, bl, acc[g], 0, 0, 0);
          }
        }
#pragma unroll
        for (int r = 0; r < 4; ++r) {
          int b = bb + r;
          float gi = acc[0][r] + preD[(size_t)((t + 1) * 64 + b) * 2048 + 0 * 512 + j] + bias[0];
          float gf = acc[1][r] + preD[(size_t)((t + 1) * 64 + b) * 2048 + 1 * 512 + j] + bias[1];
          float gg = acc[2][r] + preD[(size_t)((t + 1) * 64 + b) * 2048 + 2 * 512 + j] + bias[2];
          float go = acc[3][r] + preD[(size_t)((t + 1) * 64 + b) * 2048 + 3 * 512 + j] + bias[3];
          float c2 = sigm(gf) * c_reg[r] + sigm(gi) * tanh_f(gg);
          float h2 = sigm(go) * tanh_f(c2);
          c_reg[r] = c2;
          unsigned short hh = f2bf(h2);
          hbH[((size_t)wr * 64 + b) * 512 + j] = hh;
          hbL[((size_t)wr * 64 + b) * 512 + j] = f2bf(h2 - bf2f(hh));
          hf32[((size_t)wr * 64 + b) * 512 + j] = h2;
        }
      }
      gbar(cnt, 96u * (++ep_n));  // BAR beta
    }
  }
}

// ============================================================================
extern "C" void kernel_launch(void* const* d_in, const int* in_sizes, int n_in,
                              void* d_out, int out_size, void* d_ws, size_t ws_size,
                              hipStream_t stream) {
  (void)in_sizes; (void)n_in; (void)out_size; (void)ws_size;
  const int*   src_sents = (const int*)d_in[0];
  const int*   tgt_sents = (const int*)d_in[1];
  const float* src_emb = (const float*)d_in[2];
  const float* tgt_emb = (const float*)d_in[3];
  const float* eWihF = (const float*)d_in[4];
  const float* eWhhF = (const float*)d_in[5];
  const float* ebihF = (const float*)d_in[6];
  const float* ebhhF = (const float*)d_in[7];
  const float* eWihB = (const float*)d_in[8];
  const float* eWhhB = (const float*)d_in[9];
  const float* ebihB = (const float*)d_in[10];
  const float* ebhhB = (const float*)d_in[11];
  const float* WhI  = (const float*)d_in[12];
  const float* WcI  = (const float*)d_in[13];
  const float* dWih = (const float*)d_in[14];
  const float* dWhhf = (const float*)d_in[15];
  const float* dbih = (const float*)d_in[16];
  const float* dbhh = (const float*)d_in[17];
  const float* Watt = (const float*)d_in[18];
  const float* Wcomb = (const float*)d_in[19];
  const float* Wvoc = (const float*)d_in[20];

  char* ob = (char*)d_out;
  char* wb = (char*)d_ws;
  float* preF = (float*)(ob + OFF_PREF);
  float* preB = (float*)(ob + OFF_PREB);
  float* preD = (float*)(ob + OFF_PRED);
  unsigned short* Asrc = (unsigned short*)(ob + OFF_ASRC);
  unsigned short* Atgt = (unsigned short*)(ob + OFF_ATGT);
  unsigned short* encH = (unsigned short*)(ob + OFF_ECH);
  unsigned short* encL = (unsigned short*)(ob + OFF_ECL);
  float* epB  = (float*)(ob + OFF_EP);
  float* ehpB = (float*)(ob + OFF_EHP);
  unsigned short* wihF = (unsigned short*)(ob + OFF_WIHF);
  unsigned short* wihB = (unsigned short*)(ob + OFF_WIHB);
  unsigned short* wx   = (unsigned short*)(ob + OFF_WX);
  unsigned short* whhFh = (unsigned short*)(ob + OFF_WHHFH);
  unsigned short* whhFl = (unsigned short*)(ob + OFF_WHHFL);
  unsigned short* whhBh = (unsigned short*)(ob + OFF_WHHBH);
  unsigned short* whhBl = (unsigned short*)(ob + OFF_WHHBL);
  unsigned short* watth = (unsigned short*)(ob + OFF_WATTH);
  unsigned short* wattl = (unsigned short*)(ob + OFF_WATTL);
  unsigned short* wc1h  = (unsigned short*)(ob + OFF_WC1H);
  unsigned short* wc1l  = (unsigned short*)(ob + OFF_WC1L);
  float* wc2tf = (float*)(ob + OFF_WC2TF);
  unsigned short* woh  = (unsigned short*)(ob + OFF_WOH);
  unsigned short* wol  = (unsigned short*)(ob + OFF_WOL);
  unsigned short* dwhhh = (unsigned short*)(ob + OFF_DWHHH);
  unsigned short* dwhhl = (unsigned short*)(ob + OFF_DWHHL);
  unsigned short* whih = (unsigned short*)(ob + OFF_WHIH);
  unsigned short* whil = (unsigned short*)(ob + OFF_WHIL);
  unsigned short* wcih = (unsigned short*)(ob + OFF_WCIH);
  unsigned short* wcil = (unsigned short*)(ob + OFF_WCIL);
  unsigned short* hencH = (unsigned short*)(ob + OFF_HENCH);
  unsigned short* hencL = (unsigned short*)(ob + OFF_HENCL);
  unsigned short* hcatH = (unsigned short*)(ob + OFF_HCATH);
  unsigned short* hcatL = (unsigned short*)(ob + OFF_HCATL);
  unsigned short* ccatH = (unsigned short*)(ob + OFF_CCATH);
  unsigned short* ccatL = (unsigned short*)(ob + OFF_CCATL);
  float* dh0 = (float*)(ob + OFF_DH0);
  float* dc0 = (float*)(ob + OFF_DC0);
  unsigned short* hdbH = (unsigned short*)(ob + OFF_HDBH);
  unsigned short* hdbL = (unsigned short*)(ob + OFF_HDBL);
  float* hdf = (float*)(ob + OFF_HDF);
  unsigned short* cbcH = (unsigned short*)(ob + OFF_CBCH);
  unsigned short* cbcL = (unsigned short*)(ob + OFF_CBCL);
  unsigned int* ctrl = (unsigned int*)(ob + OFF_CTRL);
  unsigned short* comb = (unsigned short*)(wb + WOFF_COMB);
  unsigned short* wvoc = (unsigned short*)(wb + WOFF_WVOC);
  unsigned int* ctrlEnc = ctrl;
  unsigned int* ctrlDec = ctrl + 64;

  hipMemsetAsync(ctrl, 0, 4096, stream);

  auto cast = [&](const float* s, unsigned short* d, int rows, int cols, int pitch, int off) {
    int tot = rows * cols;
    k_cast_slice<<<(tot + 255) / 256, 256, 0, stream>>>(s, d, rows, cols, pitch, off);
  };
  auto castS = [&](const float* s, unsigned short* hi, unsigned short* lo,
                   int rows, int cols, int pitch, int off) {
    int tot = rows * cols;
    k_cast_split<<<(tot + 255) / 256, 256, 0, stream>>>(s, hi, lo, rows, cols, pitch, off);
  };
  cast(eWihF, wihF, 2048, 256, 256, 0);
  cast(eWihB, wihB, 2048, 256, 256, 0);
  cast(dWih,  wx,   2048, 256, 768, 512);         // dec_Wih[:, 512:768] (x part)
  cast(Wvoc,  wvoc, 16000, 512, 512, 0);
  castS(eWhhF, whhFh, whhFl, 2048, 512, 512, 0);
  castS(eWhhB, whhBh, whhBl, 2048, 512, 512, 0);
  castS(Watt,  watth, wattl, 512, 1024, 1024, 0);
  castS(Wcomb, wc1h,  wc1l,  512, 1024, 1536, 0); // W_comb[:, :1024]
  castS(dWih,  woh,   wol,   2048, 512, 768, 0);  // dec_Wih[:, :512] (o_prev part)
  castS(dWhhf, dwhhh, dwhhl, 2048, 512, 512, 0);
  castS(WhI,   whih,  whil,  512, 1024, 1024, 0);
  castS(WcI,   wcih,  wcil,  512, 1024, 1024, 0);
  k_wc2tf<<<262144 / 256, 256, 0, stream>>>(Wcomb, wc2tf);

  k_embed<<<16384, 256, 0, stream>>>(src_sents, src_emb, Asrc, 256);
  k_embed<<<8128, 256, 0, stream>>>(tgt_sents, tgt_emb, Atgt, 128);

  auto gemm = [&](const unsigned short* A, const unsigned short* W, float* C,
                  int M, int N, int K, int accum) {
    dim3 g(N / 128, (M + 127) / 128);
    k_gemm<<<g, 256, 0, stream>>>(A, W, C, M, N, K, accum);
  };
  gemm(Asrc, wihF, preF, 16384, 2048, 256, 0);
  gemm(Asrc, wihB, preB, 16384, 2048, 256, 0);
  gemm(Atgt, wx, preD, 8128, 2048, 256, 0);       // decoder x-projection

  {
    void* args[] = {(void*)&preF, (void*)&preB,
                    (void*)&whhFh, (void*)&whhFl, (void*)&whhBh, (void*)&whhBl,
                    (void*)&ebihF, (void*)&ebhhF, (void*)&ebihB, (void*)&ebhhB,
                    (void*)&hencH, (void*)&hencL, (void*)&encH, (void*)&encL,
                    (void*)&hcatH, (void*)&hcatL, (void*)&ccatH, (void*)&ccatL,
                    (void*)&ctrlEnc};
    hipLaunchCooperativeKernel((void*)k_encoder, dim3(64), dim3(256), args, 0, stream);
  }

  // 3-term split GEMMs (A_hi*W_hi + A_lo*W_hi + A_hi*W_lo)
  auto gemm3 = [&](const unsigned short* Ah, const unsigned short* Al,
                   const unsigned short* Wh, const unsigned short* Wl,
                   float* C, int M, int N, int K) {
    gemm(Ah, Wh, C, M, N, K, 0);
    gemm(Al, Wh, C, M, N, K, 1);
    gemm(Ah, Wl, C, M, N, K, 1);
  };
  gemm3(encH, encL, watth, wattl, epB, 16384, 512, 1024);   // enc_proj
  gemm3(encH, encL, wc1h,  wc1l,  ehpB, 16384, 512, 1024);  // enc_hs @ W_comb[:,:1024].T
  gemm3(hcatH, hcatL, whih, whil, dh0, 64, 512, 1024);      // dec_h0
  gemm3(ccatH, ccatL, wcih, wcil, dc0, 64, 512, 1024);      // dec_c0

  {
    void* args[] = {(void*)&preD, (void*)&woh, (void*)&wol, (void*)&dwhhh, (void*)&dwhhl,
                    (void*)&dbih, (void*)&dbhh, (void*)&dh0, (void*)&dc0,
                    (void*)&epB, (void*)&ehpB, (void*)&wc2tf,
                    (void*)&hdbH, (void*)&hdbL, (void*)&hdf,
                    (void*)&cbcH, (void*)&cbcL, (void*)&comb, (void*)&ctrlDec};
    hipLaunchCooperativeKernel((void*)k_decoder, dim3(96), dim3(512), args, 0, stream);
  }

  // final: out[b][t][:] = comb[b*127+t] @ W_vocab.T  (overwrites the d_out arena)
  gemm(comb, wvoc, (float*)d_out, 8128, 16000, 512, 0);
}